// Round 1
// baseline (89.132 us; speedup 1.0000x reference)
//
#include <hip/hip_runtime.h>

#define NL   10
#define HALO 1023            // sum of dilations 1+2+...+512
#define TILE 4096            // outputs per block
#define NT   256             // threads per block
#define NG   5               // float4 groups per thread: 5*256*4 = 5120 >= 5119
#define LDSN 5128            // tile+halo (5119) + float4 overread pad

__device__ __forceinline__ float fast_tanh(float y) {
    // tanh(y) = 1 - 2/(exp(2y)+1); exp via v_exp_f32. Saturates correctly at +/-inf.
    float e = __expf(2.0f * y);
    return 1.0f - 2.0f / (e + 1.0f);
}

__global__ __launch_bounds__(NT, 3) void rawstack_fused(
    const float* __restrict__ hin, const float* __restrict__ xin,
    const float* __restrict__ wh,  const float* __restrict__ wx,
    float* __restrict__ out, int T, int Lout)
{
    __shared__ float sh[LDSN];
    __shared__ float sx[LDSN];

    const int tid  = threadIdx.x;
    const int b    = blockIdx.y;
    const int t0   = blockIdx.x * TILE;
    const int outc = min(TILE, Lout - t0);
    const int inc  = outc + HALO;          // inputs needed; always in-bounds of row

    const float* hb = hin + (size_t)b * T + t0;
    const float* xb = xin + (size_t)b * T + t0;

    // ---- global -> LDS, float4 coalesced (rows are 16B aligned: T=131072) ----
    #pragma unroll
    for (int g = 0; g < NG; ++g) {
        const int base = (g * NT + tid) * 4;
        if (base < inc) {
            *(float4*)(sh + base) = *(const float4*)(hb + base);
            *(float4*)(sx + base) = *(const float4*)(xb + base);
        }
    }
    __syncthreads();

    // ---- 10 layers in LDS; register-stage to allow in-place update ----
    int len = inc;
    #pragma unroll
    for (int i = 0; i < NL; ++i) {
        const int d = 1 << i;              // compile-time after unroll
        const float wh0 = wh[2*i], wh1 = wh[2*i+1];
        const float wx0 = wx[2*i], wx1 = wx[2*i+1];
        const int newlen = len - d;

        float4 Hn[NG], Xn[NG];
        #pragma unroll
        for (int g = 0; g < NG; ++g) {
            const int base = (g * NT + tid) * 4;
            if (base < newlen) {
                const float4 h0 = *(const float4*)(sh + base);
                const float4 x0 = *(const float4*)(sx + base);
                float4 hd, xd;
                if (d >= 4) {              // +d is 16B aligned
                    hd = *(const float4*)(sh + base + d);
                    xd = *(const float4*)(sx + base + d);
                } else {                   // d=1,2: shift across two aligned quads
                    const float4 h1 = *(const float4*)(sh + base + 4);
                    const float4 x1 = *(const float4*)(sx + base + 4);
                    if (d == 1) {
                        hd = make_float4(h0.y, h0.z, h0.w, h1.x);
                        xd = make_float4(x0.y, x0.z, x0.w, x1.x);
                    } else {
                        hd = make_float4(h0.z, h0.w, h1.x, h1.y);
                        xd = make_float4(x0.z, x0.w, x1.x, x1.y);
                    }
                }
                float4 hn, xn;
                hn.x = wh0 * h0.x + wh1 * hd.x;
                hn.y = wh0 * h0.y + wh1 * hd.y;
                hn.z = wh0 * h0.z + wh1 * hd.z;
                hn.w = wh0 * h0.w + wh1 * hd.w;
                xn.x = fast_tanh(hn.x + wx0 * x0.x + wx1 * xd.x);
                xn.y = fast_tanh(hn.y + wx0 * x0.y + wx1 * xd.y);
                xn.z = fast_tanh(hn.z + wx0 * x0.z + wx1 * xd.z);
                xn.w = fast_tanh(hn.w + wx0 * x0.w + wx1 * xd.w);
                Hn[g] = hn; Xn[g] = xn;
            }
        }
        __syncthreads();                   // all reads of old values done
        #pragma unroll
        for (int g = 0; g < NG; ++g) {
            const int base = (g * NT + tid) * 4;
            if (base < newlen) {
                *(float4*)(sh + base) = Hn[g];
                *(float4*)(sx + base) = Xn[g];
            }
        }
        __syncthreads();                   // writes visible before next layer
        len = newlen;
    }

    // ---- store final x (rows of length Lout=130049 are NOT 16B aligned -> scalar) ----
    float* ob = out + (size_t)b * Lout + t0;
    for (int idx = tid; idx < outc; idx += NT) ob[idx] = sx[idx];
}

extern "C" void kernel_launch(void* const* d_in, const int* in_sizes, int n_in,
                              void* d_out, int out_size, void* d_ws, size_t ws_size,
                              hipStream_t stream) {
    const float* h  = (const float*)d_in[0];
    const float* x  = (const float*)d_in[1];
    const float* wh = (const float*)d_in[2];
    const float* wx = (const float*)d_in[3];
    float* out = (float*)d_out;

    const int B    = 64;
    const int T    = in_sizes[0] / B;   // 131072
    const int Lout = out_size / B;      // 130049

    dim3 grid((Lout + TILE - 1) / TILE, B);
    rawstack_fused<<<grid, NT, 0, stream>>>(h, x, wh, wx, out, T, Lout);
}

// Round 2
// 78.924 us; speedup vs baseline: 1.1293x; 1.1293x over previous
//
#include <hip/hip_runtime.h>

#define NL   10
#define C    64      // contiguous elements per lane (h and x each)
#define OUTW 3072    // valid outputs per wave = 64*C - 1024 halo
#define WPB  4       // independent waves per block (no barriers)

__device__ __forceinline__ float fast_tanh(float y) {
    // tanh(y) = 1 - 2/(exp(2y)+1);  exp(2y) = exp2(y * 2*log2(e))
    float e = __builtin_amdgcn_exp2f(y * 2.885390081777927f);
    float r = __builtin_amdgcn_rcpf(e + 1.0f);
    return fmaf(-2.0f, r, 1.0f);   // saturates correctly: e->inf => 1, e->0 => -1
}

// One layer: h[j] = wh0*h[j] + wh1*h[j+D];  x[j] = tanh(h_new[j] + wx0*x[j] + wx1*x[j+D])
// Elements beyond the lane chunk come from lane+1 (D<C) or lane+D/C (D>=C).
// Lane-index wrap produces garbage only in the invalid halo tail -- by construction safe.
template<int D>
__device__ __forceinline__ void layer_step(float (&h)[C], float (&x)[C],
        float wh0, float wh1, float wx0, float wx1, int lane)
{
    if constexpr (D < C) {
        {   // h path: pull old h[0..D) of lane+1 BEFORE overwriting (lockstep-safe)
            float t[D];
            #pragma unroll
            for (int j = 0; j < D; ++j) t[j] = __shfl(h[j], (lane + 1) & 63, 64);
            #pragma unroll
            for (int j = 0; j < C; ++j) {
                float hd = (j + D < C) ? h[j + D] : t[j + D - C];
                h[j] = fmaf(wh0, h[j], wh1 * hd);   // ascending j: h[j+D] still old
            }
        }
        {   // x path: uses NEW h[j] (just computed) and OLD x at +D
            float t[D];
            #pragma unroll
            for (int j = 0; j < D; ++j) t[j] = __shfl(x[j], (lane + 1) & 63, 64);
            #pragma unroll
            for (int j = 0; j < C; ++j) {
                float xd = (j + D < C) ? x[j + D] : t[j + D - C];
                float s  = fmaf(wx0, x[j], h[j]);
                s        = fmaf(wx1, xd, s);
                x[j] = fast_tanh(s);
            }
        }
    } else {
        constexpr int M = D / C;   // whole-chunk lane offset: 1,2,4,8
        #pragma unroll
        for (int j = 0; j < C; ++j) {
            float hd = __shfl(h[j], (lane + M) & 63, 64);  // reads pre-update h[j]
            float xd = __shfl(x[j], (lane + M) & 63, 64);
            float hn = fmaf(wh0, h[j], wh1 * hd);
            float s  = fmaf(wx0, x[j], hn);
            s        = fmaf(wx1, xd, s);
            h[j] = hn;
            x[j] = fast_tanh(s);
        }
    }
}

__global__ __launch_bounds__(256, 2) void rawstack_reg(
    const float* __restrict__ hin, const float* __restrict__ xin,
    const float* __restrict__ wh,  const float* __restrict__ wx,
    float* __restrict__ out, int T, int Lout)
{
    const int lane = threadIdx.x & 63;
    const int wv   = threadIdx.x >> 6;
    const int gw   = blockIdx.x * WPB + wv;   // wave id within this batch row
    const int b    = blockIdx.y;
    const int W    = gw * OUTW;               // window start in the row
    if (W >= Lout) return;                    // wave-uniform early out

    const float* hb = hin + (size_t)b * T;
    const float* xb = xin + (size_t)b * T;

    // ---- load window into registers: 16 float4 per array, clamped at row end ----
    float h[C], x[C];
    const int cbase = W + lane * C;
    #pragma unroll
    for (int q = 0; q < C / 4; ++q) {
        int e = cbase + q * 4;
        e = (e > T - 4) ? (T - 4) : e;        // clamp: garbage lands in invalid tail only
        float4 hv = *(const float4*)(hb + e);
        float4 xv = *(const float4*)(xb + e);
        h[q*4+0] = hv.x; h[q*4+1] = hv.y; h[q*4+2] = hv.z; h[q*4+3] = hv.w;
        x[q*4+0] = xv.x; x[q*4+1] = xv.y; x[q*4+2] = xv.z; x[q*4+3] = xv.w;
    }

    // ---- 10 layers, fully register-resident ----
    layer_step<  1>(h, x, wh[ 0], wh[ 1], wx[ 0], wx[ 1], lane);
    layer_step<  2>(h, x, wh[ 2], wh[ 3], wx[ 2], wx[ 3], lane);
    layer_step<  4>(h, x, wh[ 4], wh[ 5], wx[ 4], wx[ 5], lane);
    layer_step<  8>(h, x, wh[ 6], wh[ 7], wx[ 6], wx[ 7], lane);
    layer_step< 16>(h, x, wh[ 8], wh[ 9], wx[ 8], wx[ 9], lane);
    layer_step< 32>(h, x, wh[10], wh[11], wx[10], wx[11], lane);
    layer_step< 64>(h, x, wh[12], wh[13], wx[12], wx[13], lane);
    layer_step<128>(h, x, wh[14], wh[15], wx[14], wx[15], lane);
    layer_step<256>(h, x, wh[16], wh[17], wx[16], wx[17], lane);
    layer_step<512>(h, x, wh[18], wh[19], wx[18], wx[19], lane);

    // ---- store: lanes 0..47 hold the 3072 valid outputs ----
    if (lane < 48) {
        float* ob = out + (size_t)b * Lout;
        const int s0 = W + lane * C;
        if (s0 + C <= Lout) {
            #pragma unroll
            for (int j = 0; j < C; ++j) ob[s0 + j] = x[j];
        } else {
            #pragma unroll
            for (int j = 0; j < C; ++j) if (s0 + j < Lout) ob[s0 + j] = x[j];
        }
    }
}

extern "C" void kernel_launch(void* const* d_in, const int* in_sizes, int n_in,
                              void* d_out, int out_size, void* d_ws, size_t ws_size,
                              hipStream_t stream) {
    const float* h  = (const float*)d_in[0];
    const float* x  = (const float*)d_in[1];
    const float* wh = (const float*)d_in[2];
    const float* wx = (const float*)d_in[3];
    float* out = (float*)d_out;

    const int B    = 64;
    const int T    = in_sizes[0] / B;   // 131072
    const int Lout = out_size / B;      // 130049

    const int wavesPerRow = (Lout + OUTW - 1) / OUTW;        // 43
    const int gridx       = (wavesPerRow + WPB - 1) / WPB;   // 11

    dim3 grid(gridx, B);
    rawstack_reg<<<grid, WPB * 64, 0, stream>>>(h, x, wh, wx, out, T, Lout);
}